// Round 9
// baseline (521.745 us; speedup 1.0000x reference)
//
#include <hip/hip_runtime.h>
#include <hip/hip_fp16.h>

#define NN 50000
#define EE 800000
#define NB 782   // blocks in mm1/mm2 grids

typedef _Float16 f16x8 __attribute__((ext_vector_type(8)));
typedef _Float16 f16x4 __attribute__((ext_vector_type(4)));
typedef _Float16 f16x2 __attribute__((ext_vector_type(2)));
typedef float f32x4 __attribute__((ext_vector_type(4)));

// bit-cast helpers
__device__ __forceinline__ unsigned h2u(__half2 h) {
    union { __half2 h; unsigned u; } c; c.h = h; return c.u;
}
__device__ __forceinline__ f16x2 u2h(unsigned u) {
    union { unsigned u; f16x2 h; } c; c.u = u; return c.h;
}

// ---------------------------------------------------------------------------
// CSR build: hist -> scan (3 phase) -> scatter packed {ea f16 x7, src u16}
// ---------------------------------------------------------------------------
__global__ __launch_bounds__(256) void hist_kernel(const int* __restrict__ ei,
                                                   int* __restrict__ deg) {
    const int e = (blockIdx.x << 8) + threadIdx.x;   // 3125*256 == EE
    atomicAdd(&deg[ei[EE + e]], 1);
}

__global__ __launch_bounds__(256) void scanA_kernel(const int* __restrict__ deg,
                                                    int* __restrict__ bsum) {
    __shared__ int sm[256];
    const int t = threadIdx.x;
    const int i = (blockIdx.x << 8) + t;
    sm[t] = (i < NN) ? deg[i] : 0;
    __syncthreads();
    for (int o = 128; o > 0; o >>= 1) {
        if (t < o) sm[t] += sm[t + o];
        __syncthreads();
    }
    if (t == 0) bsum[blockIdx.x] = sm[0];
}

__global__ __launch_bounds__(256) void scanB_kernel(int* __restrict__ bsum) {
    __shared__ int sm[256];
    const int t = threadIdx.x;
    const int v = (t < 196) ? bsum[t] : 0;
    sm[t] = v;
    __syncthreads();
    for (int o = 1; o < 256; o <<= 1) {
        const int u = (t >= o) ? sm[t - o] : 0;
        __syncthreads();
        sm[t] += u;
        __syncthreads();
    }
    bsum[t] = sm[t] - v;   // exclusive scan of block sums
}

__global__ __launch_bounds__(256) void scanC_kernel(const int* __restrict__ deg,
                                                    const int* __restrict__ bsum,
                                                    int* __restrict__ off,
                                                    int* __restrict__ cur) {
    __shared__ int sm[256];
    const int t = threadIdx.x;
    const int i = (blockIdx.x << 8) + t;
    const int v = (i < NN) ? deg[i] : 0;
    sm[t] = v;
    __syncthreads();
    for (int o = 1; o < 256; o <<= 1) {
        const int u = (t >= o) ? sm[t - o] : 0;
        __syncthreads();
        sm[t] += u;
        __syncthreads();
    }
    const int excl = bsum[blockIdx.x] + sm[t] - v;
    if (i < NN) { off[i] = excl; cur[i] = excl; }
    else if (i == NN) off[NN] = excl;
}

__global__ __launch_bounds__(256) void scatter_kernel(const int* __restrict__ ei,
                                                      const float* __restrict__ ea,
                                                      int* __restrict__ cur,
                                                      int4* __restrict__ pea) {
    const int e = (blockIdx.x << 8) + threadIdx.x;   // 3125*256 == EE
    const int src = ei[e];          // < 50000 < 2^16: packed into w high bits
    const int dst = ei[EE + e];
    const float* a = ea + e * 7;
    const unsigned h0 = __half_as_ushort(__float2half(a[0]));
    const unsigned h1 = __half_as_ushort(__float2half(a[1]));
    const unsigned h2 = __half_as_ushort(__float2half(a[2]));
    const unsigned h3 = __half_as_ushort(__float2half(a[3]));
    const unsigned h4 = __half_as_ushort(__float2half(a[4]));
    const unsigned h5 = __half_as_ushort(__float2half(a[5]));
    const unsigned h6 = __half_as_ushort(__float2half(a[6]));
    const int pos = atomicAdd(&cur[dst], 1);
    pea[pos] = make_int4((int)(h0 | (h1 << 16)), (int)(h2 | (h3 << 16)),
                         (int)(h4 | (h5 << 16)), (int)(h6 | ((unsigned)src << 16)));
}

// ---------------------------------------------------------------------------
// BN stats reduce: one block per column c. part is row-major [nb][2*half].
// ---------------------------------------------------------------------------
__global__ __launch_bounds__(256) void bnstats_kernel(
    const float* __restrict__ part, const int nb, const int half,
    const float* __restrict__ g, const float* __restrict__ bb,
    float* __restrict__ scsh)
{
    __shared__ float ss[256], qq[256];
    const int c = blockIdx.x, t = threadIdx.x;
    const int stride = half << 1;
    float s = 0.f, q = 0.f;
    for (int b = t; b < nb; b += 256) {
        s += part[b * stride + c];
        q += part[b * stride + half + c];
    }
    ss[t] = s; qq[t] = q;
    __syncthreads();
    for (int o = 128; o > 0; o >>= 1) {
        if (t < o) { ss[t] += ss[t + o]; qq[t] += qq[t + o]; }
        __syncthreads();
    }
    if (t == 0) {
        const float m = ss[0] * (1.0f / NN);
        const float v = fmaxf(qq[0] * (1.0f / NN) - m * m, 0.0f);
        const float sc = g[c] * rsqrtf(v + 1e-5f);
        scsh[c] = sc;
        scsh[half + c] = bb[c] - m * sc;
    }
}

// ---------------------------------------------------------------------------
// W prep (once/launch): W1/W2 -> f16 pre-swizzled MFMA B-frag layout;
// We -> packed half2 per dim-pair Wepk[l][k][s'] (s'=0..31, dims 2s',2s'+1);
// be -> be2[l][s'].
// ---------------------------------------------------------------------------
__global__ __launch_bounds__(256) void wprep_kernel(
    const float* __restrict__ W1, const float* __restrict__ W2,
    const float* __restrict__ We, const float* __restrict__ be,
    _Float16* __restrict__ W1s, _Float16* __restrict__ W2s,
    unsigned* __restrict__ Wepk, unsigned* __restrict__ be2)
{
    const int i = (blockIdx.x << 8) + threadIdx.x;
    if (i < 40960) {
        const int l = i >> 13, j = i & 8191, k = j >> 7, n = j & 127;
        W1s[(l << 13) + ((((k >> 3) << 7) + n) << 3) + (k & 7)] = (_Float16)W1[i];
    } else if (i < 81920) {
        const int i2 = i - 40960;
        const int l = i2 >> 13, j = i2 & 8191, k = j >> 6, n = j & 63;
        W2s[(l << 13) + ((((k >> 3) << 6) + n) << 3) + (k & 7)] = (_Float16)W2[i2];
    } else if (i < 83040) {
        const int i3 = i - 81920;            // 0..1119 = [l][k][s']
        const int l = i3 / 224;
        const int r = i3 - l * 224;
        const int k = r >> 5, s = r & 31;
        const float* W = We + l * 448 + (k << 6) + (s << 1);
        Wepk[i3] = h2u(__floats2half2_rn(W[0], W[1]));
    } else if (i < 83200) {
        const int i4 = i - 83040;            // 0..159 = [l][s']
        const int l = i4 >> 5, s = i4 & 31;
        const float* B = be + (l << 6) + (s << 1);
        be2[i4] = h2u(__floats2half2_rn(B[0], B[1]));
    }
}

// ---------------------------------------------------------------------------
// h-prep: planes hA (dims 0-31), hB (dims 32-63) = f16(relu(bn2(y2))).
// Plane = 50000 x 16 dwords (3.2 MB — fits one XCD's 4 MB L2).
// ---------------------------------------------------------------------------
__global__ __launch_bounds__(256) void hprep_kernel(
    const float* __restrict__ y2, const float* __restrict__ scsh2,
    unsigned* __restrict__ hA, unsigned* __restrict__ hB)
{
    const int i4 = (blockIdx.x << 8) + threadIdx.x;   // 3125*256 == NN*64/4
    const float4 v = ((const float4*)y2)[i4];
    const int d0 = (i4 << 2) & 63;
    const int n = i4 >> 4;
    const float a = fmaxf(fmaf(v.x, scsh2[d0 + 0], scsh2[64 + d0 + 0]), 0.f);
    const float b = fmaxf(fmaf(v.y, scsh2[d0 + 1], scsh2[64 + d0 + 1]), 0.f);
    const float c = fmaxf(fmaf(v.z, scsh2[d0 + 2], scsh2[64 + d0 + 2]), 0.f);
    const float d = fmaxf(fmaf(v.w, scsh2[d0 + 3], scsh2[64 + d0 + 3]), 0.f);
    unsigned* p = (d0 < 32) ? hA : hB;
    const int w = (n << 4) + ((d0 & 31) >> 1);
    p[w] = h2u(__floats2half2_rn(a, b));
    p[w + 1] = h2u(__floats2half2_rn(c, d));
}

// Layer-0 h-prep: planes from f16(nemb[x]).
__global__ __launch_bounds__(256) void hprep0_kernel(
    const int* __restrict__ x, const float* __restrict__ nemb,
    unsigned* __restrict__ hA, unsigned* __restrict__ hB)
{
    const int i4 = (blockIdx.x << 8) + threadIdx.x;   // 3125*256 == NN*64/4
    const int n = i4 >> 4;
    const int d0 = (i4 << 2) & 63;
    const float4 v = ((const float4*)nemb)[(x[n] << 4) + (i4 & 15)];
    unsigned* p = (d0 < 32) ? hA : hB;
    const int w = (n << 4) + ((d0 & 31) >> 1);
    p[w] = h2u(__floats2half2_rn(v.x, v.y));
    p[w + 1] = h2u(__floats2half2_rn(v.z, v.w));
}

// ---------------------------------------------------------------------------
// Gather (dim-split plane pass): 4 nodes per wave x 16 lanes; lane owns one
// dword (2 dims) of the 64B plane row — h gather = 1 cache line, L2-resident
// (3.2 MB plane < 4 MB XCD L2). pea broadcast per 16-lane group. Two passes
// per layer (plane A then B). Edge math: 7 v_pk_fma_f16 per edge.
// ---------------------------------------------------------------------------
__global__ __launch_bounds__(256) void gather_kernel(
    const int* __restrict__ off, const int4* __restrict__ pea,
    const unsigned* __restrict__ hp,       // plane: NN x 16 dwords
    const unsigned* __restrict__ Wp,       // Wepk + l*224 + pass*16
    const unsigned* __restrict__ bep,      // be2  + l*32  + pass*16
    const float* __restrict__ epsp,
    unsigned* __restrict__ zp)             // z plane: padded rows x 16 dwords
{
    const int t = threadIdx.x;
    const int lane = t & 63;
    const int s = lane & 15;
    const int n = (blockIdx.x << 4) + (((t >> 6) << 2) | (lane >> 4)); // 3125*16

    const f16x2 w0 = u2h(Wp[s]),        w1 = u2h(Wp[32 + s]),
                w2 = u2h(Wp[64 + s]),   w3 = u2h(Wp[96 + s]),
                w4 = u2h(Wp[128 + s]),  w5 = u2h(Wp[160 + s]),
                w6 = u2h(Wp[192 + s]);
    const f16x2 beh = u2h(bep[s]);

    const int e0 = off[n], e1 = off[n + 1];
    const int deg = e1 - e0;
    int dm = max(deg, __shfl_xor(deg, 16));
    dm = max(dm, __shfl_xor(dm, 32));

    float aLo = 0.f, aHi = 0.f;
    for (int i = 0; i < dm; i += 8) {
        int4 pk[8]; int vld[8];
#pragma unroll
        for (int j = 0; j < 8; ++j) {
            const int ej = e0 + i + j;
            vld[j] = (ej < e1);
            pk[j] = pea[vld[j] ? ej : 0];   // clamp to 0: always in-bounds
        }
        unsigned hv[8];
#pragma unroll
        for (int j = 0; j < 8; ++j) {
            const int src = (int)(((unsigned)pk[j].w) >> 16);
            hv[j] = hp[(src << 4) + s];
        }
#pragma unroll
        for (int j = 0; j < 8; ++j) {
            const f16x2 a01 = u2h((unsigned)pk[j].x);
            const f16x2 a23 = u2h((unsigned)pk[j].y);
            const f16x2 a45 = u2h((unsigned)pk[j].z);
            const f16x2 a6x = u2h((unsigned)pk[j].w);
            f16x2 ee = beh;
            ee += (f16x2){a01[0], a01[0]} * w0;
            ee += (f16x2){a01[1], a01[1]} * w1;
            ee += (f16x2){a23[0], a23[0]} * w2;
            ee += (f16x2){a23[1], a23[1]} * w3;
            ee += (f16x2){a45[0], a45[0]} * w4;
            ee += (f16x2){a45[1], a45[1]} * w5;
            ee += (f16x2){a6x[0], a6x[0]} * w6;
            f16x2 m2 = u2h(hv[j]) + ee;
            const _Float16 zz = (_Float16)0.f;
            m2 = (f16x2){ m2[0] > zz ? m2[0] : zz, m2[1] > zz ? m2[1] : zz };
            const float mf = vld[j] ? 1.f : 0.f;
            aLo = fmaf(mf, (float)m2[0], aLo);
            aHi = fmaf(mf, (float)m2[1], aHi);
        }
    }
    const f16x2 hn2 = u2h(hp[(n << 4) + s]);
    const float e1f = 1.0f + epsp[0];
    const float zLo = fmaf(e1f, (float)hn2[0], aLo);
    const float zHi = fmaf(e1f, (float)hn2[1], aHi);
    zp[(n << 4) + s] = h2u(__floats2half2_rn(zLo, zHi));
}

// ---------------------------------------------------------------------------
// MM1 (MFMA f16): y1 = z @ W1 + b1, f16 out. A-frag k-window 0 comes from
// plane zA, window 1 from zB (plane row == fragment k-range). B-frags direct
// from pre-swizzled W1s (L2-hot). In-register stats.
// ---------------------------------------------------------------------------
__global__ __launch_bounds__(256) void mm1_kernel(
    const _Float16* __restrict__ zA, const _Float16* __restrict__ zB,
    const _Float16* __restrict__ W1s,
    const float* __restrict__ b1p, _Float16* __restrict__ y1h,
    float* __restrict__ part1)
{
    __shared__ float smS[4][128], smQ[4][128];
    const int t = threadIdx.x;
    const int wv = t >> 6, lane = t & 63;
    const int q = lane >> 4, ln = lane & 15;
    const int r0 = blockIdx.x << 6;

    const int rowm = r0 + (wv << 4) + ln;
    const f16x8 af0 = *(const f16x8*)(zA + rowm * 32 + (q << 3));
    const f16x8 af1 = *(const f16x8*)(zB + rowm * 32 + (q << 3));

    f32x4 acc[8];
#pragma unroll
    for (int n0 = 0; n0 < 8; ++n0) acc[n0] = (f32x4){0.f, 0.f, 0.f, 0.f};
#pragma unroll
    for (int n0 = 0; n0 < 8; ++n0) {
        const f16x8 bf0 = *(const f16x8*)(W1s + (((q << 7) + (n0 << 4) + ln) << 3));
        const f16x8 bf1 = *(const f16x8*)(W1s + ((((4 + q) << 7) + (n0 << 4) + ln) << 3));
        acc[n0] = __builtin_amdgcn_mfma_f32_16x16x32_f16(af0, bf0, acc[n0], 0, 0, 0);
        acc[n0] = __builtin_amdgcn_mfma_f32_16x16x32_f16(af1, bf1, acc[n0], 0, 0, 0);
    }

    const int baseRow = r0 + (wv << 4) + (q << 2);
#pragma unroll
    for (int n0 = 0; n0 < 8; ++n0) {
        const int col = (n0 << 4) + ln;
        const float bb = b1p[col];
        float s = 0.f, sq = 0.f;
#pragma unroll
        for (int rg = 0; rg < 4; ++rg) {
            const int row = baseRow + rg;
            const float y = acc[n0][rg] + bb;
            y1h[row * 128 + col] = (_Float16)y;
            const float m = (row < NN) ? 1.f : 0.f;
            s = fmaf(m, y, s); sq = fmaf(m, y * y, sq);
        }
        s += __shfl_xor(s, 16); s += __shfl_xor(s, 32);
        sq += __shfl_xor(sq, 16); sq += __shfl_xor(sq, 32);
        if (lane < 16) { smS[wv][col] = s; smQ[wv][col] = sq; }
    }
    __syncthreads();
    if (t < 128) {
        const float s = smS[0][t] + smS[1][t] + smS[2][t] + smS[3][t];
        const float q2 = smQ[0][t] + smQ[1][t] + smQ[2][t] + smQ[3][t];
        part1[(blockIdx.x << 8) + t] = s;
        part1[(blockIdx.x << 8) + 128 + t] = q2;
    }
}

// ---------------------------------------------------------------------------
// MM2 (MFMA f16): y2 = relu(bn1(y1h)) @ W2 + b2 (f32 out). Block = 64 rows.
// y2 row-aliases y1h (A reads complete before epilogue stores).
// ---------------------------------------------------------------------------
__global__ __launch_bounds__(256) void mm2_kernel(
    const _Float16* __restrict__ y1h, const float* __restrict__ scsh1,
    const _Float16* __restrict__ W2s, const float* __restrict__ b2,
    float* __restrict__ y2, float* __restrict__ part2)
{
    __shared__ float smS[4][64], smQ[4][64];
    const int t = threadIdx.x;
    const int wv = t >> 6, lane = t & 63;
    const int q = lane >> 4, ln = lane & 15;
    const int r0 = blockIdx.x << 6;

    const int rowm = r0 + (wv << 4) + ln;
    f16x8 af[4];
#pragma unroll
    for (int ks = 0; ks < 4; ++ks) {
        const int k0 = (ks << 5) + (q << 3);
        const f16x8 raw = *(const f16x8*)(y1h + rowm * 128 + k0);
        const float4 scA = *(const float4*)(scsh1 + k0);
        const float4 scB = *(const float4*)(scsh1 + k0 + 4);
        const float4 shA = *(const float4*)(scsh1 + 128 + k0);
        const float4 shB = *(const float4*)(scsh1 + 128 + k0 + 4);
        const float sc[8] = {scA.x, scA.y, scA.z, scA.w, scB.x, scB.y, scB.z, scB.w};
        const float sh[8] = {shA.x, shA.y, shA.z, shA.w, shB.x, shB.y, shB.z, shB.w};
        f16x8 a;
#pragma unroll
        for (int j = 0; j < 8; ++j)
            a[j] = (_Float16)fmaxf(fmaf((float)raw[j], sc[j], sh[j]), 0.f);
        af[ks] = a;
    }

    f32x4 acc[4];
#pragma unroll
    for (int n0 = 0; n0 < 4; ++n0) acc[n0] = (f32x4){0.f, 0.f, 0.f, 0.f};
#pragma unroll
    for (int n0 = 0; n0 < 4; ++n0) {
#pragma unroll
        for (int ks = 0; ks < 4; ++ks) {
            const f16x8 bf = *(const f16x8*)(
                W2s + (((((ks << 2) + q) << 6) + (n0 << 4) + ln) << 3));
            acc[n0] = __builtin_amdgcn_mfma_f32_16x16x32_f16(af[ks], bf, acc[n0], 0, 0, 0);
        }
    }

    const int baseRow = r0 + (wv << 4) + (q << 2);
#pragma unroll
    for (int n0 = 0; n0 < 4; ++n0) {
        const int col = (n0 << 4) + ln;
        const float bb = b2[col];
        float s = 0.f, sq = 0.f;
#pragma unroll
        for (int rg = 0; rg < 4; ++rg) {
            const int row = baseRow + rg;
            const float y = acc[n0][rg] + bb;
            y2[row * 64 + col] = y;
            const float m = (row < NN) ? 1.f : 0.f;
            s = fmaf(m, y, s); sq = fmaf(m, y * y, sq);
        }
        s += __shfl_xor(s, 16); s += __shfl_xor(s, 32);
        sq += __shfl_xor(sq, 16); sq += __shfl_xor(sq, 32);
        if (lane < 16) { smS[wv][col] = s; smQ[wv][col] = sq; }
    }
    __syncthreads();
    if (t < 64) {
        const float s = smS[0][t] + smS[1][t] + smS[2][t] + smS[3][t];
        const float q2 = smQ[0][t] + smQ[1][t] + smQ[2][t] + smQ[3][t];
        part2[(blockIdx.x << 7) + t] = s;
        part2[(blockIdx.x << 7) + 64 + t] = q2;
    }
}

// ---------------------------------------------------------------------------
// Final: out = bn2(y2) of layer 4 (no relu on last layer).
// ---------------------------------------------------------------------------
__global__ __launch_bounds__(256) void final_kernel(
    const float* __restrict__ y2, const float* __restrict__ scsh2,
    float* __restrict__ out)
{
    const int i = (blockIdx.x << 8) + threadIdx.x;
    if (i >= NN * 64) return;
    const int d = i & 63;
    out[i] = fmaf(y2[i], scsh2[d], scsh2[64 + d]);
}

extern "C" void kernel_launch(void* const* d_in, const int* in_sizes, int n_in,
                              void* d_out, int out_size, void* d_ws, size_t ws_size,
                              hipStream_t stream)
{
    const int*   x    = (const int*)d_in[0];
    const int*   ei   = (const int*)d_in[1];
    const float* ea   = (const float*)d_in[2];
    const float* nemb = (const float*)d_in[3];
    const float* We   = (const float*)d_in[4];
    const float* be   = (const float*)d_in[5];
    const float* eps  = (const float*)d_in[6];
    const float* W1   = (const float*)d_in[7];
    const float* b1   = (const float*)d_in[8];
    const float* g1   = (const float*)d_in[9];
    const float* bb1  = (const float*)d_in[10];
    const float* W2   = (const float*)d_in[11];
    const float* b2   = (const float*)d_in[12];
    const float* g2   = (const float*)d_in[13];
    const float* bb2  = (const float*)d_in[14];
    float* out = (float*)d_out;

    // workspace layout (4-byte word offsets); total 10,098,688 words = 40.4 MB
    int*      iws   = (int*)d_ws;
    float*    fws   = (float*)d_ws;
    int*      off   = iws + 0;          // 50001
    int*      deg   = iws + 50048;      // 50000
    int*      cur   = iws + 100096;     // 50000
    int*      bsum  = iws + 150144;     // 256
    float*    scsh1 = fws + 150400;     // 256 (sc128, sh128)
    float*    scsh2 = fws + 150656;     // 128 (sc64, sh64)
    float*    part1 = fws + 150784;     // 782*256 (row-major [bid][256])
    float*    part2 = fws + 350976;     // 782*128 (row-major [bid][128])
    _Float16* W1s   = (_Float16*)(fws + 451072);  // 5*8192 f16 swizzled
    _Float16* W2s   = (_Float16*)(fws + 471552);  // 5*8192 f16 swizzled
    unsigned* Wepk  = (unsigned*)(fws + 492032);  // 5*7*32 half2 (1120 words)
    unsigned* be2   = (unsigned*)(fws + 493152);  // 5*32 half2 (160 words)
    int4*     pea   = (int4*)(iws + 493312);      // 800000 x 16B
    unsigned* zA    = (unsigned*)(fws + 3693312); // 50048 x 16 dwords (plane)
    unsigned* zB    = (unsigned*)(fws + 4494080); // 50048 x 16 dwords (plane)
    _Float16* y1h   = (_Float16*)(fws + 5294848); // 50048 x 128 f16 } row-
    float*    y2    = fws + 5294848;              // 50048 x 64 f32  } aliased
    unsigned* hA    = (unsigned*)(fws + 8497920); // 50000 x 16 dwords (plane)
    unsigned* hB    = (unsigned*)(fws + 9297920); // 50000 x 16 dwords (plane)

    hipMemsetAsync(deg, 0, 50000 * sizeof(int), stream);

    hist_kernel   <<<3125, 256, 0, stream>>>(ei, deg);
    scanA_kernel  <<<196,  256, 0, stream>>>(deg, bsum);
    scanB_kernel  <<<1,    256, 0, stream>>>(bsum);
    scanC_kernel  <<<196,  256, 0, stream>>>(deg, bsum, off, cur);
    scatter_kernel<<<3125, 256, 0, stream>>>(ei, ea, cur, pea);
    wprep_kernel  <<<325,  256, 0, stream>>>(W1, W2, We, be, W1s, W2s, Wepk, be2);
    hprep0_kernel <<<3125, 256, 0, stream>>>(x, nemb, hA, hB);

    for (int l = 0; l < 5; ++l) {
        gather_kernel<<<3125, 256, 0, stream>>>(
            off, pea, hA, Wepk + l * 224, be2 + l * 32, eps + l, zA);
        gather_kernel<<<3125, 256, 0, stream>>>(
            off, pea, hB, Wepk + l * 224 + 16, be2 + l * 32 + 16, eps + l, zB);

        mm1_kernel<<<NB, 256, 0, stream>>>((const _Float16*)zA, (const _Float16*)zB,
                                           W1s + l * 8192, b1 + l * 128, y1h, part1);

        bnstats_kernel<<<128, 256, 0, stream>>>(part1, NB, 128,
                                                g1 + l * 128, bb1 + l * 128, scsh1);

        mm2_kernel<<<NB, 256, 0, stream>>>(y1h, scsh1, W2s + l * 8192, b2 + l * 64,
                                           y2, part2);

        bnstats_kernel<<<64, 256, 0, stream>>>(part2, NB, 64,
                                               g2 + l * 64, bb2 + l * 64, scsh2);

        if (l < 4)
            hprep_kernel<<<3125, 256, 0, stream>>>(y2, scsh2, hA, hB);
    }

    final_kernel<<<12500, 256, 0, stream>>>(y2, scsh2, out);
}

// Round 10
// 486.476 us; speedup vs baseline: 1.0725x; 1.0725x over previous
//
#include <hip/hip_runtime.h>
#include <hip/hip_fp16.h>

#define NN 50000
#define EE 800000
#define NB 782   // blocks in mm1/mm2 grids

typedef _Float16 f16x8 __attribute__((ext_vector_type(8)));
typedef _Float16 f16x4 __attribute__((ext_vector_type(4)));
typedef _Float16 f16x2 __attribute__((ext_vector_type(2)));
typedef float f32x4 __attribute__((ext_vector_type(4)));

// bit-cast helpers
__device__ __forceinline__ unsigned h2u(__half2 h) {
    union { __half2 h; unsigned u; } c; c.h = h; return c.u;
}
__device__ __forceinline__ f16x2 u2h(unsigned u) {
    union { unsigned u; f16x2 h; } c; c.u = u; return c.h;
}

// ---------------------------------------------------------------------------
// CSR build: hist -> scan of PADDED degrees (multiple of 8) -> scatter ->
// dummy-fill tails. Dummy edge = {ea=0, src=50000}; h16 row 50000 = -65504
// so relu(h_dummy + ee) == 0 and the gather loop needs NO masks.
// ---------------------------------------------------------------------------
__global__ __launch_bounds__(256) void hist_kernel(const int* __restrict__ ei,
                                                   int* __restrict__ deg) {
    const int e = (blockIdx.x << 8) + threadIdx.x;   // 3125*256 == EE
    atomicAdd(&deg[ei[EE + e]], 1);
}

__global__ __launch_bounds__(256) void scanA_kernel(const int* __restrict__ deg,
                                                    int* __restrict__ bsum) {
    __shared__ int sm[256];
    const int t = threadIdx.x;
    const int i = (blockIdx.x << 8) + t;
    sm[t] = (i < NN) ? ((deg[i] + 7) & ~7) : 0;    // padded degree
    __syncthreads();
    for (int o = 128; o > 0; o >>= 1) {
        if (t < o) sm[t] += sm[t + o];
        __syncthreads();
    }
    if (t == 0) bsum[blockIdx.x] = sm[0];
}

__global__ __launch_bounds__(256) void scanB_kernel(int* __restrict__ bsum) {
    __shared__ int sm[256];
    const int t = threadIdx.x;
    const int v = (t < 196) ? bsum[t] : 0;
    sm[t] = v;
    __syncthreads();
    for (int o = 1; o < 256; o <<= 1) {
        const int u = (t >= o) ? sm[t - o] : 0;
        __syncthreads();
        sm[t] += u;
        __syncthreads();
    }
    bsum[t] = sm[t] - v;   // exclusive scan of block sums
}

__global__ __launch_bounds__(256) void scanC_kernel(const int* __restrict__ deg,
                                                    const int* __restrict__ bsum,
                                                    int* __restrict__ off,
                                                    int* __restrict__ cur) {
    __shared__ int sm[256];
    const int t = threadIdx.x;
    const int i = (blockIdx.x << 8) + t;
    const int v = (i < NN) ? ((deg[i] + 7) & ~7) : 0;   // padded degree
    sm[t] = v;
    __syncthreads();
    for (int o = 1; o < 256; o <<= 1) {
        const int u = (t >= o) ? sm[t - o] : 0;
        __syncthreads();
        sm[t] += u;
        __syncthreads();
    }
    const int excl = bsum[blockIdx.x] + sm[t] - v;
    if (i < NN) { off[i] = excl; cur[i] = excl; }
    else if (i == NN) off[NN] = excl;
}

__global__ __launch_bounds__(256) void scatter_kernel(const int* __restrict__ ei,
                                                      const float* __restrict__ ea,
                                                      int* __restrict__ cur,
                                                      int4* __restrict__ pea) {
    const int e = (blockIdx.x << 8) + threadIdx.x;   // 3125*256 == EE
    const int src = ei[e];          // < 50000 < 2^16: packed into w high bits
    const int dst = ei[EE + e];
    const float* a = ea + e * 7;
    const unsigned h0 = __half_as_ushort(__float2half(a[0]));
    const unsigned h1 = __half_as_ushort(__float2half(a[1]));
    const unsigned h2 = __half_as_ushort(__float2half(a[2]));
    const unsigned h3 = __half_as_ushort(__float2half(a[3]));
    const unsigned h4 = __half_as_ushort(__float2half(a[4]));
    const unsigned h5 = __half_as_ushort(__float2half(a[5]));
    const unsigned h6 = __half_as_ushort(__float2half(a[6]));
    const int pos = atomicAdd(&cur[dst], 1);
    pea[pos] = make_int4((int)(h0 | (h1 << 16)), (int)(h2 | (h3 << 16)),
                         (int)(h4 | (h5 << 16)), (int)(h6 | ((unsigned)src << 16)));
}

// fill tails with dummy edges; also write the h16 dummy row (-65504).
__global__ __launch_bounds__(256) void fill_kernel(
    const int* __restrict__ off, const int* __restrict__ cur,
    int4* __restrict__ pea, unsigned* __restrict__ h32)
{
    const int i = (blockIdx.x << 8) + threadIdx.x;   // 1563*256 >= 400032
    if (i < 32) h32[(NN << 5) + i] = 0xFBFFFBFFu;    // row 50000 = -65504 f16
    if (i >= NN * 8) return;
    const int n = i >> 3, j = i & 7;
    const int pos = cur[n] + j;
    if (pos < off[n + 1])
        pea[pos] = make_int4(0, 0, 0, (int)(((unsigned)NN) << 16));
}

// ---------------------------------------------------------------------------
// BN stats reduce: one block per column c. part is row-major [nb][2*half].
// ---------------------------------------------------------------------------
__global__ __launch_bounds__(256) void bnstats_kernel(
    const float* __restrict__ part, const int nb, const int half,
    const float* __restrict__ g, const float* __restrict__ bb,
    float* __restrict__ scsh)
{
    __shared__ float ss[256], qq[256];
    const int c = blockIdx.x, t = threadIdx.x;
    const int stride = half << 1;
    float s = 0.f, q = 0.f;
    for (int b = t; b < nb; b += 256) {
        s += part[b * stride + c];
        q += part[b * stride + half + c];
    }
    ss[t] = s; qq[t] = q;
    __syncthreads();
    for (int o = 128; o > 0; o >>= 1) {
        if (t < o) { ss[t] += ss[t + o]; qq[t] += qq[t + o]; }
        __syncthreads();
    }
    if (t == 0) {
        const float m = ss[0] * (1.0f / NN);
        const float v = fmaxf(qq[0] * (1.0f / NN) - m * m, 0.0f);
        const float sc = g[c] * rsqrtf(v + 1e-5f);
        scsh[c] = sc;
        scsh[half + c] = bb[c] - m * sc;
    }
}

// ---------------------------------------------------------------------------
// W prep (once/launch): W1/W2 -> f16 pre-swizzled MFMA B-frag layout;
// We -> packed half2 per dim-pair Wepk; be -> be2.
// ---------------------------------------------------------------------------
__global__ __launch_bounds__(256) void wprep_kernel(
    const float* __restrict__ W1, const float* __restrict__ W2,
    const float* __restrict__ We, const float* __restrict__ be,
    _Float16* __restrict__ W1s, _Float16* __restrict__ W2s,
    unsigned* __restrict__ Wepk, unsigned* __restrict__ be2)
{
    const int i = (blockIdx.x << 8) + threadIdx.x;
    if (i < 40960) {
        const int l = i >> 13, j = i & 8191, k = j >> 7, n = j & 127;
        W1s[(l << 13) + ((((k >> 3) << 7) + n) << 3) + (k & 7)] = (_Float16)W1[i];
    } else if (i < 81920) {
        const int i2 = i - 40960;
        const int l = i2 >> 13, j = i2 & 8191, k = j >> 6, n = j & 63;
        W2s[(l << 13) + ((((k >> 3) << 6) + n) << 3) + (k & 7)] = (_Float16)W2[i2];
    } else if (i < 83040) {
        const int i3 = i - 81920;            // 0..1119 = [l][k][s]
        const int l = i3 / 224;
        const int r = i3 - l * 224;
        const int k = r >> 5, s = r & 31;
        const float* W = We + l * 448 + (k << 6) + (s << 1);
        Wepk[i3] = h2u(__floats2half2_rn(W[0], W[1]));
    } else if (i < 83200) {
        const int i4 = i - 83040;            // 0..159 = [l][s]
        const int l = i4 >> 5, s = i4 & 31;
        const float* B = be + (l << 6) + (s << 1);
        be2[i4] = h2u(__floats2half2_rn(B[0], B[1]));
    }
}

// ---------------------------------------------------------------------------
// h-prep: h16 = f16(relu(bn2(y2))).  (rows 0..49999; dummy row untouched)
// ---------------------------------------------------------------------------
__global__ __launch_bounds__(256) void hprep_kernel(
    const float* __restrict__ y2, const float* __restrict__ scsh2,
    __half* __restrict__ h16)
{
    const int i4 = (blockIdx.x << 8) + threadIdx.x;   // 3125*256 == NN*64/4
    const float4 v = ((const float4*)y2)[i4];
    const int d0 = (i4 << 2) & 63;
    const float a = fmaxf(fmaf(v.x, scsh2[d0 + 0], scsh2[64 + d0 + 0]), 0.f);
    const float b = fmaxf(fmaf(v.y, scsh2[d0 + 1], scsh2[64 + d0 + 1]), 0.f);
    const float c = fmaxf(fmaf(v.z, scsh2[d0 + 2], scsh2[64 + d0 + 2]), 0.f);
    const float d = fmaxf(fmaf(v.w, scsh2[d0 + 3], scsh2[64 + d0 + 3]), 0.f);
    *(int2*)(h16 + (i4 << 2)) =
        make_int2((int)h2u(__floats2half2_rn(a, b)),
                  (int)h2u(__floats2half2_rn(c, d)));
}

// Layer-0 h-prep: h16 = f16(nemb[x]).
__global__ __launch_bounds__(256) void hprep0_kernel(
    const int* __restrict__ x, const float* __restrict__ nemb,
    __half* __restrict__ h16)
{
    const int i4 = (blockIdx.x << 8) + threadIdx.x;   // 3125*256 == NN*64/4
    const int n = i4 >> 4;
    const float4 v = ((const float4*)nemb)[(x[n] << 4) + (i4 & 15)];
    *(int2*)(h16 + (i4 << 2)) =
        make_int2((int)h2u(__floats2half2_rn(v.x, v.y)),
                  (int)h2u(__floats2half2_rn(v.z, v.w)));
}

// ---------------------------------------------------------------------------
// Gather (half-wave packed, maskless): 2 nodes/wave, lane owns 2 dims (half2).
// CSR padded to x8 with dummy edges (msg==0), so the 8-edge batch needs no
// masks/clamps: per 2-edge slot = 2 loads + 10 pk-ops. Per-node loop bound
// handled by exec-mask divergence. acc in packed f16.
// ---------------------------------------------------------------------------
__global__ __launch_bounds__(256) void gather_kernel(
    const int* __restrict__ off, const int4* __restrict__ pea,
    const unsigned* __restrict__ h32,      // h16 rows viewed as 32 dwords
    const unsigned* __restrict__ Wepk, const unsigned* __restrict__ be2,
    const float* __restrict__ epsp,
    unsigned* __restrict__ z32)            // z16 rows viewed as 32 dwords
{
    const int t = threadIdx.x;
    const int lane = t & 63;
    const int s = lane & 31;
    const int n = (blockIdx.x << 3) + ((t >> 6) << 1) + (lane >> 5); // 6250*8

    const f16x2 w0 = u2h(Wepk[s]),       w1 = u2h(Wepk[32 + s]),
                w2 = u2h(Wepk[64 + s]),  w3 = u2h(Wepk[96 + s]),
                w4 = u2h(Wepk[128 + s]), w5 = u2h(Wepk[160 + s]),
                w6 = u2h(Wepk[192 + s]);
    const f16x2 beh = u2h(be2[s]);

    const int e0 = off[n], e1 = off[n + 1];   // padded: count % 8 == 0

    f16x2 acc2 = (f16x2){(_Float16)0.f, (_Float16)0.f};
    for (int e = e0; e < e1; e += 8) {
        int4 pk[8];
#pragma unroll
        for (int j = 0; j < 8; ++j) pk[j] = pea[e + j];
        unsigned hv[8];
#pragma unroll
        for (int j = 0; j < 8; ++j) {
            const int src = (int)(((unsigned)pk[j].w) >> 16);
            hv[j] = h32[(src << 5) + s];
        }
#pragma unroll
        for (int j = 0; j < 8; ++j) {
            const f16x2 a01 = u2h((unsigned)pk[j].x);
            const f16x2 a23 = u2h((unsigned)pk[j].y);
            const f16x2 a45 = u2h((unsigned)pk[j].z);
            const f16x2 a6x = u2h((unsigned)pk[j].w);
            f16x2 ee = beh;
            ee += (f16x2){a01[0], a01[0]} * w0;
            ee += (f16x2){a01[1], a01[1]} * w1;
            ee += (f16x2){a23[0], a23[0]} * w2;
            ee += (f16x2){a23[1], a23[1]} * w3;
            ee += (f16x2){a45[0], a45[0]} * w4;
            ee += (f16x2){a45[1], a45[1]} * w5;
            ee += (f16x2){a6x[0], a6x[0]} * w6;
            f16x2 m2 = u2h(hv[j]) + ee;
            const _Float16 zz = (_Float16)0.f;
            m2 = (f16x2){ m2[0] > zz ? m2[0] : zz, m2[1] > zz ? m2[1] : zz };
            acc2 += m2;
        }
    }
    const f16x2 hn2 = u2h(h32[(n << 5) + s]);
    const float e1f = 1.0f + epsp[0];
    const float zLo = fmaf(e1f, (float)hn2[0], (float)acc2[0]);
    const float zHi = fmaf(e1f, (float)hn2[1], (float)acc2[1]);
    z32[(n << 5) + s] = h2u(__floats2half2_rn(zLo, zHi));
}

// ---------------------------------------------------------------------------
// MM1 (MFMA f16): y1 = z16 @ W1 + b1, f16 out. Block = 64 rows, 4 waves;
// B-frags direct from pre-swizzled W1s (L2-hot). In-register stats.
// ---------------------------------------------------------------------------
__global__ __launch_bounds__(256) void mm1_kernel(
    const _Float16* __restrict__ z16, const _Float16* __restrict__ W1s,
    const float* __restrict__ b1p, _Float16* __restrict__ y1h,
    float* __restrict__ part1)
{
    __shared__ float smS[4][128], smQ[4][128];
    const int t = threadIdx.x;
    const int wv = t >> 6, lane = t & 63;
    const int q = lane >> 4, ln = lane & 15;
    const int r0 = blockIdx.x << 6;

    const int rowm = r0 + (wv << 4) + ln;
    const f16x8 af0 = *(const f16x8*)(z16 + rowm * 64 + (q << 3));
    const f16x8 af1 = *(const f16x8*)(z16 + rowm * 64 + 32 + (q << 3));

    f32x4 acc[8];
#pragma unroll
    for (int n0 = 0; n0 < 8; ++n0) acc[n0] = (f32x4){0.f, 0.f, 0.f, 0.f};
#pragma unroll
    for (int n0 = 0; n0 < 8; ++n0) {
        const f16x8 bf0 = *(const f16x8*)(W1s + (((q << 7) + (n0 << 4) + ln) << 3));
        const f16x8 bf1 = *(const f16x8*)(W1s + ((((4 + q) << 7) + (n0 << 4) + ln) << 3));
        acc[n0] = __builtin_amdgcn_mfma_f32_16x16x32_f16(af0, bf0, acc[n0], 0, 0, 0);
        acc[n0] = __builtin_amdgcn_mfma_f32_16x16x32_f16(af1, bf1, acc[n0], 0, 0, 0);
    }

    const int baseRow = r0 + (wv << 4) + (q << 2);
#pragma unroll
    for (int n0 = 0; n0 < 8; ++n0) {
        const int col = (n0 << 4) + ln;
        const float bb = b1p[col];
        float s = 0.f, sq = 0.f;
#pragma unroll
        for (int rg = 0; rg < 4; ++rg) {
            const int row = baseRow + rg;
            const float y = acc[n0][rg] + bb;
            y1h[row * 128 + col] = (_Float16)y;
            const float m = (row < NN) ? 1.f : 0.f;
            s = fmaf(m, y, s); sq = fmaf(m, y * y, sq);
        }
        s += __shfl_xor(s, 16); s += __shfl_xor(s, 32);
        sq += __shfl_xor(sq, 16); sq += __shfl_xor(sq, 32);
        if (lane < 16) { smS[wv][col] = s; smQ[wv][col] = sq; }
    }
    __syncthreads();
    if (t < 128) {
        const float s = smS[0][t] + smS[1][t] + smS[2][t] + smS[3][t];
        const float q2 = smQ[0][t] + smQ[1][t] + smQ[2][t] + smQ[3][t];
        part1[(blockIdx.x << 8) + t] = s;
        part1[(blockIdx.x << 8) + 128 + t] = q2;
    }
}

// ---------------------------------------------------------------------------
// MM2 (MFMA f16): y2 = relu(bn1(y1h)) @ W2 + b2 (f32 out). Block = 64 rows.
// y2 row-aliases y1h (A reads complete before epilogue stores).
// ---------------------------------------------------------------------------
__global__ __launch_bounds__(256) void mm2_kernel(
    const _Float16* __restrict__ y1h, const float* __restrict__ scsh1,
    const _Float16* __restrict__ W2s, const float* __restrict__ b2,
    float* __restrict__ y2, float* __restrict__ part2)
{
    __shared__ float smS[4][64], smQ[4][64];
    const int t = threadIdx.x;
    const int wv = t >> 6, lane = t & 63;
    const int q = lane >> 4, ln = lane & 15;
    const int r0 = blockIdx.x << 6;

    const int rowm = r0 + (wv << 4) + ln;
    f16x8 af[4];
#pragma unroll
    for (int ks = 0; ks < 4; ++ks) {
        const int k0 = (ks << 5) + (q << 3);
        const f16x8 raw = *(const f16x8*)(y1h + rowm * 128 + k0);
        const float4 scA = *(const float4*)(scsh1 + k0);
        const float4 scB = *(const float4*)(scsh1 + k0 + 4);
        const float4 shA = *(const float4*)(scsh1 + 128 + k0);
        const float4 shB = *(const float4*)(scsh1 + 128 + k0 + 4);
        const float sc[8] = {scA.x, scA.y, scA.z, scA.w, scB.x, scB.y, scB.z, scB.w};
        const float sh[8] = {shA.x, shA.y, shA.z, shA.w, shB.x, shB.y, shB.z, shB.w};
        f16x8 a;
#pragma unroll
        for (int j = 0; j < 8; ++j)
            a[j] = (_Float16)fmaxf(fmaf((float)raw[j], sc[j], sh[j]), 0.f);
        af[ks] = a;
    }

    f32x4 acc[4];
#pragma unroll
    for (int n0 = 0; n0 < 4; ++n0) acc[n0] = (f32x4){0.f, 0.f, 0.f, 0.f};
#pragma unroll
    for (int n0 = 0; n0 < 4; ++n0) {
#pragma unroll
        for (int ks = 0; ks < 4; ++ks) {
            const f16x8 bf = *(const f16x8*)(
                W2s + (((((ks << 2) + q) << 6) + (n0 << 4) + ln) << 3));
            acc[n0] = __builtin_amdgcn_mfma_f32_16x16x32_f16(af[ks], bf, acc[n0], 0, 0, 0);
        }
    }

    const int baseRow = r0 + (wv << 4) + (q << 2);
#pragma unroll
    for (int n0 = 0; n0 < 4; ++n0) {
        const int col = (n0 << 4) + ln;
        const float bb = b2[col];
        float s = 0.f, sq = 0.f;
#pragma unroll
        for (int rg = 0; rg < 4; ++rg) {
            const int row = baseRow + rg;
            const float y = acc[n0][rg] + bb;
            y2[row * 64 + col] = y;
            const float m = (row < NN) ? 1.f : 0.f;
            s = fmaf(m, y, s); sq = fmaf(m, y * y, sq);
        }
        s += __shfl_xor(s, 16); s += __shfl_xor(s, 32);
        sq += __shfl_xor(sq, 16); sq += __shfl_xor(sq, 32);
        if (lane < 16) { smS[wv][col] = s; smQ[wv][col] = sq; }
    }
    __syncthreads();
    if (t < 64) {
        const float s = smS[0][t] + smS[1][t] + smS[2][t] + smS[3][t];
        const float q2 = smQ[0][t] + smQ[1][t] + smQ[2][t] + smQ[3][t];
        part2[(blockIdx.x << 7) + t] = s;
        part2[(blockIdx.x << 7) + 64 + t] = q2;
    }
}

// ---------------------------------------------------------------------------
// Final: out = bn2(y2) of layer 4 (no relu on last layer).
// ---------------------------------------------------------------------------
__global__ __launch_bounds__(256) void final_kernel(
    const float* __restrict__ y2, const float* __restrict__ scsh2,
    float* __restrict__ out)
{
    const int i = (blockIdx.x << 8) + threadIdx.x;
    if (i >= NN * 64) return;
    const int d = i & 63;
    out[i] = fmaf(y2[i], scsh2[d], scsh2[64 + d]);
}

extern "C" void kernel_launch(void* const* d_in, const int* in_sizes, int n_in,
                              void* d_out, int out_size, void* d_ws, size_t ws_size,
                              hipStream_t stream)
{
    const int*   x    = (const int*)d_in[0];
    const int*   ei   = (const int*)d_in[1];
    const float* ea   = (const float*)d_in[2];
    const float* nemb = (const float*)d_in[3];
    const float* We   = (const float*)d_in[4];
    const float* be   = (const float*)d_in[5];
    const float* eps  = (const float*)d_in[6];
    const float* W1   = (const float*)d_in[7];
    const float* b1   = (const float*)d_in[8];
    const float* g1   = (const float*)d_in[9];
    const float* bb1  = (const float*)d_in[10];
    const float* W2   = (const float*)d_in[11];
    const float* b2   = (const float*)d_in[12];
    const float* g2   = (const float*)d_in[13];
    const float* bb2  = (const float*)d_in[14];
    float* out = (float*)d_out;

    // workspace layout (4-byte word offsets); total 11,497,952 words = 46.0 MB
    int*      iws   = (int*)d_ws;
    float*    fws   = (float*)d_ws;
    int*      off   = iws + 0;          // 50001
    int*      deg   = iws + 50048;      // 50000
    int*      cur   = iws + 100096;     // 50000
    int*      bsum  = iws + 150144;     // 256
    float*    scsh1 = fws + 150400;     // 256 (sc128, sh128)
    float*    scsh2 = fws + 150656;     // 128 (sc64, sh64)
    float*    part1 = fws + 150784;     // 782*256 (row-major [bid][256])
    float*    part2 = fws + 350976;     // 782*128 (row-major [bid][128])
    _Float16* W1s   = (_Float16*)(fws + 451072);  // 5*8192 f16 swizzled
    _Float16* W2s   = (_Float16*)(fws + 471552);  // 5*8192 f16 swizzled
    unsigned* Wepk  = (unsigned*)(fws + 492032);  // 5*7*32 half2 (1120 words)
    unsigned* be2   = (unsigned*)(fws + 493152);  // 5*32 half2 (160 words)
    int4*     pea   = (int4*)(iws + 493312);      // 1,150,000 x 16B (padded CSR)
    _Float16* z16   = (_Float16*)(fws + 5093312); // 50048 x 64 f16 (padded rows)
    _Float16* y1h   = (_Float16*)(fws + 6694848); // 50048 x 128 f16 } row-
    float*    y2    = fws + 6694848;              // 50048 x 64 f32  } aliased
    __half*   h16   = (__half*)(fws + 9897920);   // 50001 x 64 f16 (+dummy row)

    hipMemsetAsync(deg, 0, 50000 * sizeof(int), stream);

    hist_kernel   <<<3125, 256, 0, stream>>>(ei, deg);
    scanA_kernel  <<<196,  256, 0, stream>>>(deg, bsum);
    scanB_kernel  <<<1,    256, 0, stream>>>(bsum);
    scanC_kernel  <<<196,  256, 0, stream>>>(deg, bsum, off, cur);
    scatter_kernel<<<3125, 256, 0, stream>>>(ei, ea, cur, pea);
    fill_kernel   <<<1563, 256, 0, stream>>>(off, cur, pea, (unsigned*)h16);
    wprep_kernel  <<<325,  256, 0, stream>>>(W1, W2, We, be, W1s, W2s, Wepk, be2);
    hprep0_kernel <<<3125, 256, 0, stream>>>(x, nemb, h16);

    for (int l = 0; l < 5; ++l) {
        gather_kernel<<<6250, 256, 0, stream>>>(
            off, pea, (const unsigned*)h16, Wepk + l * 224, be2 + l * 32,
            eps + l, (unsigned*)z16);

        mm1_kernel<<<NB, 256, 0, stream>>>(z16, W1s + l * 8192, b1 + l * 128,
                                           y1h, part1);

        bnstats_kernel<<<128, 256, 0, stream>>>(part1, NB, 128,
                                                g1 + l * 128, bb1 + l * 128, scsh1);

        mm2_kernel<<<NB, 256, 0, stream>>>(y1h, scsh1, W2s + l * 8192, b2 + l * 64,
                                           y2, part2);

        bnstats_kernel<<<64, 256, 0, stream>>>(part2, NB, 64,
                                               g2 + l * 64, bb2 + l * 64, scsh2);

        if (l < 4)
            hprep_kernel<<<3125, 256, 0, stream>>>(y2, scsh2, h16);
    }

    final_kernel<<<12500, 256, 0, stream>>>(y2, scsh2, out);
}